// Round 11
// baseline (476.939 us; speedup 1.0000x reference)
//
#include <hip/hip_runtime.h>

#define SEQ   512
#define BATCH 4
#define NN    128
#define HID   64
#define G4    256   // 4*HID gates per layer
#define MAGIC 0x13579BDF

// Fast activations: v_exp_f32 + v_rcp_f32 (abs err ~1e-6, threshold is 1e-3)
__device__ __forceinline__ float frcp(float x)  { return __builtin_amdgcn_rcpf(x); }
__device__ __forceinline__ float fsigm(float x) { return frcp(1.f + __expf(-x)); }
__device__ __forceinline__ float ftanh(float x) { return 1.f - 2.f * frcp(1.f + __expf(2.f * x)); }
__device__ __forceinline__ float lrelu(float x) { return x > 0.f ? x : 0.2f * x; }
__device__ __forceinline__ float dot4f(float4 w, float4 h) {
  return fmaf(w.x, h.x, fmaf(w.y, h.y, fmaf(w.z, h.z, w.w * h.w)));
}
__device__ __forceinline__ void pin4(float4& v) {
  asm volatile("" : "+v"(v.x), "+v"(v.y), "+v"(v.z), "+v"(v.w));
}
// Quad butterfly sum via self-inverse quad_perm: 0xB1={1,0,3,2}, 0x4E={2,3,0,1}.
__device__ __forceinline__ float qsum(float x) {
  x += __int_as_float(__builtin_amdgcn_update_dpp(
      0, __float_as_int(x), 0xB1, 0xF, 0xF, true));
  x += __int_as_float(__builtin_amdgcn_update_dpp(
      0, __float_as_int(x), 0x4E, 0xF, 0xF, true));
  return x;
}
__device__ __forceinline__ float dotacc(const float4* w, const float4* h, float a) {
#pragma unroll
  for (int c = 0; c < 4; ++c) {
    a = fmaf(w[c].x, h[c].x, a);
    a = fmaf(w[c].y, h[c].y, a);
    a = fmaf(w[c].z, h[c].z, a);
    a = fmaf(w[c].w, h[c].w, a);
  }
  return a;
}

// ---------------------------------------------------------------------------
// fused_all: ONE kernel, 132 blocks x 768 threads.
//   blocks 0-3   : 2-layer LSTM scan (R6/R10 structure, untouched) + heads,
//                  gated on X0-chunk flags (producer-consumer overlap).
//   blocks 4-131 : X0 chunk (blockIdx-4)*16 rows; blocks 4-7 also GAT for
//                  batch blockIdx-4.
// Sync: producer stores -> __syncthreads (per-thread vmcnt(0) drain before
// s_barrier => all block stores in L2) -> tid0 agent-scope RELEASE store of
// MAGIC (L2 writeback). Consumer: tid0 agent-scope ACQUIRE fetch_add(0)
// (RMW executes at the device coherence point -> cannot read a stale cached
// MAGIC from the previous bench iteration) -> __syncthreads -> block reads.
// ws is poisoned 0xAA each iteration: 0xAAAAAAAA != MAGIC, so flags are
// safely "not ready" until produced. Capacity: 132 blocks, 12 waves + 82KB
// LDS each -> <=1-2 blocks/CU on 256 CUs -> all co-resident (no deadlock).
// ---------------------------------------------------------------------------
__global__ __attribute__((amdgpu_flat_work_group_size(768, 768),
                          amdgpu_waves_per_eu(3, 3)))
void fused_all(
    const float* __restrict__ x, const int* __restrict__ adj,
    const float* __restrict__ emb_w, const float* __restrict__ emb_b,
    const float* __restrict__ W1, const float* __restrict__ a1,
    const float* __restrict__ W2, const float* __restrict__ a2,
    const float* __restrict__ Wih0, const float* __restrict__ Whh0,
    const float* __restrict__ bih0, const float* __restrict__ bhh0,
    const float* __restrict__ Wih1, const float* __restrict__ Whh1,
    const float* __restrict__ bih1, const float* __restrict__ bhh1,
    const float* __restrict__ dw1, const float* __restrict__ db1,
    const float* __restrict__ dw2, const float* __restrict__ db2,
    const float* __restrict__ rw1, const float* __restrict__ rb1,
    const float* __restrict__ rw2, const float* __restrict__ rb2,
    const float* __restrict__ vw1, const float* __restrict__ vb1,
    const float* __restrict__ vw2, const float* __restrict__ vb2,
    float* __restrict__ X0T, float* __restrict__ xg,
    int* __restrict__ flags, float* __restrict__ out)
{
  const int bid = blockIdx.x;
  const int tid = threadIdx.x;

  if (bid >= 4) {
    // =================== PRODUCER: X0 chunk ===================
    const int chunk = bid - 4;
    __shared__ __align__(16) float xls[NN];
    {
      const int g = tid >> 1, half = tid & 1;
      float4 w4[16];
      if (tid < 512) {
        const float4* wp = reinterpret_cast<const float4*>(Wih0 + g * NN + half * 64);
#pragma unroll
        for (int i = 0; i < 16; ++i) w4[i] = wp[i];
#pragma unroll
        for (int i = 0; i < 16; ++i) pin4(w4[i]);
      }
      const float bsum = (tid < 512) ? (bih0[g] + bhh0[g]) : 0.f;
      const int r0 = chunk * 16;
      for (int r = r0; r < r0 + 16; ++r) {
        const int tt = r >> 2, b = r & 3;
        if (tid < NN) xls[tid] = x[(b * SEQ + tt) * NN + tid];
        __syncthreads();
        if (tid < 512) {
          const float4* hp = reinterpret_cast<const float4*>(&xls[half * 64]);
          float p0 = 0.f, p1 = 0.f, p2 = 0.f, p3 = 0.f;
#pragma unroll
          for (int k = 0; k < 16; k += 4) {
            p0 += dot4f(w4[k],     hp[k]);
            p1 += dot4f(w4[k + 1], hp[k + 1]);
            p2 += dot4f(w4[k + 2], hp[k + 2]);
            p3 += dot4f(w4[k + 3], hp[k + 3]);
          }
          float p = (p0 + p1) + (p2 + p3);
          p += __shfl_xor(p, 1);
          if (half == 0) X0T[r * G4 + (g & 63) * 4 + (g >> 6)] = p + bsum;
        }
        __syncthreads();
      }
    }
    // publish chunk (stores drained by the barrier above)
    if (tid == 0)
      __hip_atomic_store(&flags[chunk], MAGIC, __ATOMIC_RELEASE,
                         __HIP_MEMORY_SCOPE_AGENT);
    if (bid >= 8) return;

    // =================== GAT (blocks 4-7, batch b) ===================
    const int b = bid - 4;
    __shared__ float adjm[NN * 129];
    __shared__ __align__(16) float gxls[NN];
    __shared__ float u[16], v[16];
    __shared__ float Wh2[NN][9];
    __shared__ float f1b[NN], f2b[NN];
    __shared__ float p[NN];

    for (int idx = tid; idx < NN * NN; idx += 768)
      adjm[(idx >> 7) * 129 + (idx & 127)] = (adj[idx] > 0) ? 1.f : 0.f;
    if (tid < NN) gxls[tid] = x[(b * SEQ + (SEQ - 1)) * NN + tid];
    if (tid < 16) {
      float uu = 0.f, vv = 0.f;
      for (int fp = 0; fp < 16; ++fp) {
        uu += emb_w[fp] * W1[fp * 16 + tid];
        vv += emb_b[fp] * W1[fp * 16 + tid];
      }
      u[tid] = uu; v[tid] = vv;
    }
    __syncthreads();
    float s1 = 0.f, t1 = 0.f, s2 = 0.f, t2 = 0.f;
    for (int f = 0; f < 16; ++f) {
      s1 += u[f] * a1[f];      t1 += v[f] * a1[f];
      s2 += u[f] * a1[16 + f]; t2 += v[f] * a1[16 + f];
    }
    if (tid < NN) {
      const int i = tid;
      const float f1i = gxls[i] * s1 + t1;
      float m = -1e30f;
      for (int j = 0; j < NN; ++j)
        if (adjm[i * 129 + j] != 0.f)
          m = fmaxf(m, lrelu(f1i + gxls[j] * s2 + t2));
      float ssum = 0.f, ps = 0.f;
      for (int j = 0; j < NN; ++j)
        if (adjm[i * 129 + j] != 0.f) {
          const float wgt = __expf(lrelu(f1i + gxls[j] * s2 + t2) - m);
          ssum += wgt; ps += wgt * gxls[j];
        }
      p[i] = ps / ssum;
    }
    __syncthreads();
    if (tid < NN) {
      const int i = tid;
      float xg1[16];
#pragma unroll
      for (int f = 0; f < 16; ++f) {
        const float ov = p[i] * u[f] + v[f];
        xg1[f] = ov > 0.f ? ov : expm1f(ov);
      }
      float wrow[8];
#pragma unroll
      for (int f2 = 0; f2 < 8; ++f2) wrow[f2] = 0.f;
#pragma unroll
      for (int f = 0; f < 16; ++f) {
        const float xv = xg1[f];
#pragma unroll
        for (int f2 = 0; f2 < 8; ++f2) wrow[f2] += xv * W2[f * 8 + f2];
      }
      float fb1 = 0.f, fb2 = 0.f;
#pragma unroll
      for (int f2 = 0; f2 < 8; ++f2) {
        Wh2[i][f2] = wrow[f2];
        fb1 += wrow[f2] * a2[f2];
        fb2 += wrow[f2] * a2[8 + f2];
      }
      f1b[i] = fb1; f2b[i] = fb2;
    }
    __syncthreads();
    if (tid < NN) {
      const int i = tid;
      const float fi = f1b[i];
      float m = -1e30f;
      for (int j = 0; j < NN; ++j)
        if (adjm[i * 129 + j] != 0.f)
          m = fmaxf(m, lrelu(fi + f2b[j]));
      float ssum = 0.f;
      float o[8];
#pragma unroll
      for (int f2 = 0; f2 < 8; ++f2) o[f2] = 0.f;
      for (int j = 0; j < NN; ++j)
        if (adjm[i * 129 + j] != 0.f) {
          const float wgt = __expf(lrelu(fi + f2b[j]) - m);
          ssum += wgt;
#pragma unroll
          for (int f2 = 0; f2 < 8; ++f2) o[f2] += wgt * Wh2[j][f2];
        }
      const float inv = 1.f / ssum;
#pragma unroll
      for (int f2 = 0; f2 < 8; ++f2)
        xg[b * (NN * 8) + i * 8 + f2] = o[f2] * inv;
    }
    __syncthreads();
    if (tid == 0)
      __hip_atomic_store(&flags[128 + b], MAGIC, __ATOMIC_RELEASE,
                         __HIP_MEMORY_SCOPE_AGENT);
    return;
  }

  // =================== CONSUMER: LSTM scan + heads (blocks 0-3) ============
  const int b   = bid;
  const int t   = tid;
  const int grp = t >> 8;            // 0,1,2 (wave-aligned)
  const int r   = t & 255;           // == uu*4 + q2
  const int uu  = r >> 2, q2 = r & 3;

  __shared__ __align__(16) float hb[2][2][HID];   // [buf][layer][unit]
  __shared__ __align__(16) float P1[2][G4];       // dbuf ih-partials
  __shared__ float cbuf[1088];
  __shared__ float hidc[96];

  const float* Wsrc = (grp == 0) ? Whh0 : (grp == 1) ? Wih1 : Whh1;
  float4 w[4][4];
#pragma unroll
  for (int j = 0; j < 4; ++j) {
    const int row = (uu + 64 * j) * HID + 16 * q2;
#pragma unroll
    for (int c = 0; c < 4; ++c)
      w[j][c] = *reinterpret_cast<const float4*>(Wsrc + row + 4 * c);
  }
  float4 b1v = make_float4(0.f, 0.f, 0.f, 0.f);
  if (grp == 2) {
    b1v.x = bih1[uu]       + bhh1[uu];
    b1v.y = bih1[uu + 64]  + bhh1[uu + 64];
    b1v.z = bih1[uu + 128] + bhh1[uu + 128];
    b1v.w = bih1[uu + 192] + bhh1[uu + 192];
  }

  if (t < 256) reinterpret_cast<float*>(hb)[t] = 0.f;   // both buffers
  float cst = 0.f;
  const float* X0b = X0T + b * G4 + uu * 4;
  int c_ok = -1;

  // Gate on chunk NEED (uniform): t0 acquire-RMW polls, block barrier syncs.
#define WAITC(NEED)                                                            \
  do {                                                                         \
    if ((NEED) > c_ok) {                                                       \
      if (t == 0) {                                                            \
        for (int c = c_ok + 1; c <= (NEED); ++c)                               \
          while (__hip_atomic_fetch_add(&flags[c], 0, __ATOMIC_ACQUIRE,        \
                                        __HIP_MEMORY_SCOPE_AGENT) != MAGIC) {} \
      }                                                                        \
      __syncthreads();                                                         \
      c_ok = (NEED);                                                           \
    }                                                                          \
  } while (0)

  WAITC(0);
  float4 cur = make_float4(0.f, 0.f, 0.f, 0.f);
  if (grp == 0) cur = *reinterpret_cast<const float4*>(X0b);
  __syncthreads();

#define LSTM_STEP(TT, RB, WB)                                                  \
  do {                                                                         \
    const float4* hp = reinterpret_cast<const float4*>(                        \
        (grp == 2) ? &hb[RB][1][0] : &hb[RB][0][0]);                           \
    float4 hq[4];                                                              \
    hq[0] = hp[4 * q2 + 0]; hq[1] = hp[4 * q2 + 1];                            \
    hq[2] = hp[4 * q2 + 2]; hq[3] = hp[4 * q2 + 3];                            \
    float4 p1v = make_float4(0.f, 0.f, 0.f, 0.f);                              \
    if (grp == 2) p1v = *reinterpret_cast<const float4*>(&P1[1 - (RB)][uu * 4]); \
    float4 nxt = cur;                                                          \
    if (grp == 0 && (TT) + 1 < SEQ)                                            \
      nxt = *reinterpret_cast<const float4*>(X0b + ((TT) + 1) * (BATCH * G4)); \
    float A0 = dotacc(w[0], hq, 0.f);                                          \
    float A1 = dotacc(w[1], hq, 0.f);                                          \
    float A2 = dotacc(w[2], hq, 0.f);                                          \
    float A3 = dotacc(w[3], hq, 0.f);                                          \
    const float S0 = qsum(A0), S1 = qsum(A1), S2 = qsum(A2), S3 = qsum(A3);    \
    if (grp == 0) {                                                            \
      if ((TT) < SEQ) {                                                        \
        const float gi = fsigm(S0 + cur.x);                                    \
        const float gf = fsigm(S1 + cur.y);                                    \
        const float gg = ftanh(S2 + cur.z);                                    \
        const float go = fsigm(S3 + cur.w);                                    \
        cst = fmaf(gf, cst, gi * gg);                                          \
        if (q2 == 0) hb[WB][0][uu] = go * ftanh(cst);                          \
      }                                                                        \
    } else if (grp == 1) {                                                     \
      if ((TT) >= 1 && (TT) <= SEQ) {                                          \
        const float sel = (q2 == 0) ? S0 : (q2 == 1) ? S1 : (q2 == 2) ? S2 : S3; \
        P1[RB][r] = sel;                                                       \
      }                                                                        \
    } else {                                                                   \
      if ((TT) >= 2) {                                                         \
        const float gi = fsigm(S0 + p1v.x + b1v.x);                            \
        const float gf = fsigm(S1 + p1v.y + b1v.y);                            \
        const float gg = ftanh(S2 + p1v.z + b1v.z);                            \
        const float go = fsigm(S3 + p1v.w + b1v.w);                            \
        cst = fmaf(gf, cst, gi * gg);                                          \
        if (q2 == 0) hb[WB][1][uu] = go * ftanh(cst);                          \
      }                                                                        \
    }                                                                          \
    cur = nxt;                                                                 \
    __syncthreads();                                                           \
  } while (0)

  for (int tt = 0; tt < SEQ + 2; tt += 2) {   // TT = 0..513
    {
      const int rmax = ((tt + 2) < SEQ) ? (tt + 2) : (SEQ - 1);
      WAITC((rmax * 4 + 3) >> 4);
    }
#pragma unroll
    for (int j = 0; j < 4; ++j) {
      pin4(w[j][0]); pin4(w[j][1]); pin4(w[j][2]); pin4(w[j][3]);
    }
    LSTM_STEP(tt, 0, 1);
    LSTM_STEP(tt + 1, 1, 0);
  }
#undef LSTM_STEP
#undef WAITC
  // grp2's last write (TT=513, WB=0): hb[0][1][*] = h1[SEQ-1] = xl_out.

  // wait for this batch's GAT result
  if (t == 0) {
    while (__hip_atomic_fetch_add(&flags[128 + b], 0, __ATOMIC_ACQUIRE,
                                  __HIP_MEMORY_SCOPE_AGENT) != MAGIC) {}
  }
  __syncthreads();

  // ---------------- fused heads: c = [h1(64) | xg_b(1024)] ----------------
  if (t < 64) cbuf[t] = hb[0][1][t];
  for (int k = t; k < 1024; k += 768) cbuf[64 + k] = xg[b * 1024 + k];
  __syncthreads();
  if (t < 96) {
    const int head = t >> 5, h = t & 31;
    const float* w1 = (head == 0) ? dw1 : (head == 1) ? rw1 : vw1;
    const float* b1 = (head == 0) ? db1 : (head == 1) ? rb1 : vb1;
    float a0 = 0.f, a1v = 0.f, a2v = 0.f, a3v = 0.f;
    for (int k = 0; k < 1088; k += 4) {
      a0  = fmaf(cbuf[k],     w1[k * 32 + h],       a0);
      a1v = fmaf(cbuf[k + 1], w1[(k + 1) * 32 + h], a1v);
      a2v = fmaf(cbuf[k + 2], w1[(k + 2) * 32 + h], a2v);
      a3v = fmaf(cbuf[k + 3], w1[(k + 3) * 32 + h], a3v);
    }
    hidc[head * 32 + h] = fmaxf(b1[h] + ((a0 + a1v) + (a2v + a3v)), 0.f);
  }
  __syncthreads();
  if (t < 4) {
    const int head2 = (t < 2) ? t : 2;
    const int o = (t < 2) ? 0 : (t - 2);
    const int odim = (t < 2) ? 1 : 2;
    const float* w2  = (head2 == 0) ? dw2 : (head2 == 1) ? rw2 : vw2;
    const float* b2p = (head2 == 0) ? db2 : (head2 == 1) ? rb2 : vb2;
    float acc = b2p[o];
    for (int hh = 0; hh < 32; ++hh)
      acc = fmaf(hidc[head2 * 32 + hh], w2[hh * odim + o], acc);
    const int off = (t == 0) ? b : (t == 1) ? (4 + b) : (8 + 2 * b + o);
    out[off] = acc;   // [dir(4) | ret(4) | vol(4x2)] flat
  }
}

// ---------------------------------------------------------------------------
extern "C" void kernel_launch(void* const* d_in, const int* in_sizes, int n_in,
                              void* d_out, int out_size, void* d_ws, size_t ws_size,
                              hipStream_t stream) {
  const float* x     = (const float*)d_in[0];
  const int*   adj   = (const int*)  d_in[1];
  const float* emb_w = (const float*)d_in[2];
  const float* emb_b = (const float*)d_in[3];
  const float* g1W   = (const float*)d_in[4];
  const float* g1a   = (const float*)d_in[5];
  const float* g2W   = (const float*)d_in[6];
  const float* g2a   = (const float*)d_in[7];
  const float* Wih0  = (const float*)d_in[8];
  const float* Whh0  = (const float*)d_in[9];
  const float* bih0  = (const float*)d_in[10];
  const float* bhh0  = (const float*)d_in[11];
  const float* Wih1  = (const float*)d_in[12];
  const float* Whh1  = (const float*)d_in[13];
  const float* bih1  = (const float*)d_in[14];
  const float* bhh1  = (const float*)d_in[15];
  const float* dw1 = (const float*)d_in[16]; const float* db1 = (const float*)d_in[17];
  const float* dw2 = (const float*)d_in[18]; const float* db2 = (const float*)d_in[19];
  const float* rw1 = (const float*)d_in[20]; const float* rb1 = (const float*)d_in[21];
  const float* rw2 = (const float*)d_in[22]; const float* rb2 = (const float*)d_in[23];
  const float* vw1 = (const float*)d_in[24]; const float* vb1 = (const float*)d_in[25];
  const float* vw2 = (const float*)d_in[26]; const float* vb2 = (const float*)d_in[27];

  float* ws = (float*)d_ws;
  float* X0 = ws;                          // SEQ*BATCH*256 floats = 2 MB (transposed)
  float* xg = ws + SEQ * BATCH * G4;       // 4096 floats
  int*  flg = (int*)(xg + BATCH * NN * 8); // 132 flag ints (0xAA-poisoned = not ready)
  float* out = (float*)d_out;

  hipLaunchKernelGGL(fused_all, dim3(132), dim3(768), 0, stream,
                     x, adj, emb_w, emb_b, g1W, g1a, g2W, g2a,
                     Wih0, Whh0, bih0, bhh0, Wih1, Whh1, bih1, bhh1,
                     dw1, db1, dw2, db2, rw1, rb1, rw2, rb2,
                     vw1, vb1, vw2, vb2,
                     X0, xg, flg, out);
}

// Round 12
// 449.832 us; speedup vs baseline: 1.0603x; 1.0603x over previous
//
#include <hip/hip_runtime.h>

#define SEQ   512
#define BATCH 4
#define NN    128
#define HID   64
#define G4    256   // 4*HID gates per layer
#define MAGIC 0x13579BDF

// Fast activations: v_exp_f32 + v_rcp_f32 (abs err ~1e-6, threshold is 1e-3)
__device__ __forceinline__ float frcp(float x)  { return __builtin_amdgcn_rcpf(x); }
__device__ __forceinline__ float fsigm(float x) { return frcp(1.f + __expf(-x)); }
__device__ __forceinline__ float ftanh(float x) { return 1.f - 2.f * frcp(1.f + __expf(2.f * x)); }
__device__ __forceinline__ float lrelu(float x) { return x > 0.f ? x : 0.2f * x; }
__device__ __forceinline__ float dot4f(float4 w, float4 h) {
  return fmaf(w.x, h.x, fmaf(w.y, h.y, fmaf(w.z, h.z, w.w * h.w)));
}
__device__ __forceinline__ void pin4(float4& v) {
  asm volatile("" : "+v"(v.x), "+v"(v.y), "+v"(v.z), "+v"(v.w));
}
// Quad butterfly sum via self-inverse quad_perm: 0xB1={1,0,3,2}, 0x4E={2,3,0,1}.
__device__ __forceinline__ float qsum(float x) {
  x += __int_as_float(__builtin_amdgcn_update_dpp(
      0, __float_as_int(x), 0xB1, 0xF, 0xF, true));
  x += __int_as_float(__builtin_amdgcn_update_dpp(
      0, __float_as_int(x), 0x4E, 0xF, 0xF, true));
  return x;
}
__device__ __forceinline__ float dotacc(const float4* w, const float4* h, float a) {
#pragma unroll
  for (int c = 0; c < 4; ++c) {
    a = fmaf(w[c].x, h[c].x, a);
    a = fmaf(w[c].y, h[c].y, a);
    a = fmaf(w[c].z, h[c].z, a);
    a = fmaf(w[c].w, h[c].w, a);
  }
  return a;
}

// ---------------------------------------------------------------------------
// fused_all: ONE kernel, 132 blocks x 768 threads.
//   blocks 0-3   : LSTM scan (R6 structure, untouched) + heads, gated on
//                  banded X0 flags.
//   blocks 4-131 : X0 producer, BAND-INTERLEAVED (R12 fix): block c produces
//                  timesteps {c, c+128, c+256, c+384}. flags[c] (RELEASE)
//                  after the FIRST timestep (~2.5us -> no consumer start
//                  stall), flags[128+c] after all four. Blocks 4-7 then GAT
//                  (flags[256+b]).
// Consumer frontier invariant: timestep t needs flag f=t (t<256) or
// f=128+(t&127) (t>=256); both monotone -> "all f <= min(tt,255)".
// Polls are 32-wide parallel acquire-RMWs (threads 0-31, one batch per 32
// steps, 9 batches total) instead of R11's 128 serial RMWs.
// RMW (not plain load) so the poll executes at the L2 coherence point and
// can't spin on a stale L1 line. ws 0xAA-poison != MAGIC -> flags start
// "not ready" every launch.
// ---------------------------------------------------------------------------
__global__ __attribute__((amdgpu_flat_work_group_size(768, 768),
                          amdgpu_waves_per_eu(3, 3)))
void fused_all(
    const float* __restrict__ x, const int* __restrict__ adj,
    const float* __restrict__ emb_w, const float* __restrict__ emb_b,
    const float* __restrict__ W1, const float* __restrict__ a1,
    const float* __restrict__ W2, const float* __restrict__ a2,
    const float* __restrict__ Wih0, const float* __restrict__ Whh0,
    const float* __restrict__ bih0, const float* __restrict__ bhh0,
    const float* __restrict__ Wih1, const float* __restrict__ Whh1,
    const float* __restrict__ bih1, const float* __restrict__ bhh1,
    const float* __restrict__ dw1, const float* __restrict__ db1,
    const float* __restrict__ dw2, const float* __restrict__ db2,
    const float* __restrict__ rw1, const float* __restrict__ rb1,
    const float* __restrict__ rw2, const float* __restrict__ rb2,
    const float* __restrict__ vw1, const float* __restrict__ vb1,
    const float* __restrict__ vw2, const float* __restrict__ vb2,
    float* __restrict__ X0T, float* __restrict__ xg,
    int* __restrict__ flags, float* __restrict__ out)
{
  const int bid = blockIdx.x;
  const int tid = threadIdx.x;

  if (bid >= 4) {
    // =================== PRODUCER: band-interleaved X0 ===================
    const int c = bid - 4;
    __shared__ __align__(16) float xls[NN];
    {
      const int g = tid >> 1, half = tid & 1;
      float4 w4[16];
      if (tid < 512) {
        const float4* wp = reinterpret_cast<const float4*>(Wih0 + g * NN + half * 64);
#pragma unroll
        for (int i = 0; i < 16; ++i) w4[i] = wp[i];
#pragma unroll
        for (int i = 0; i < 16; ++i) pin4(w4[i]);
      }
      const float bsum = (tid < 512) ? (bih0[g] + bhh0[g]) : 0.f;
      for (int phase = 0; phase < 4; ++phase) {
        const int T = c + 128 * phase;
        for (int bb = 0; bb < BATCH; ++bb) {
          if (tid < NN) xls[tid] = x[(bb * SEQ + T) * NN + tid];
          __syncthreads();
          if (tid < 512) {
            const float4* hp = reinterpret_cast<const float4*>(&xls[half * 64]);
            float p0 = 0.f, p1 = 0.f, p2 = 0.f, p3 = 0.f;
#pragma unroll
            for (int k = 0; k < 16; k += 4) {
              p0 += dot4f(w4[k],     hp[k]);
              p1 += dot4f(w4[k + 1], hp[k + 1]);
              p2 += dot4f(w4[k + 2], hp[k + 2]);
              p3 += dot4f(w4[k + 3], hp[k + 3]);
            }
            float p = (p0 + p1) + (p2 + p3);
            p += __shfl_xor(p, 1);
            if (half == 0)
              X0T[(4 * T + bb) * G4 + (g & 63) * 4 + (g >> 6)] = p + bsum;
          }
          __syncthreads();   // drains this block's X0 stores (vmcnt(0) before s_barrier)
        }
        if (tid == 0 && phase == 0)
          __hip_atomic_store(&flags[c], MAGIC, __ATOMIC_RELEASE,
                             __HIP_MEMORY_SCOPE_AGENT);
        if (tid == 0 && phase == 3)
          __hip_atomic_store(&flags[128 + c], MAGIC, __ATOMIC_RELEASE,
                             __HIP_MEMORY_SCOPE_AGENT);
      }
    }
    if (bid >= 8) return;

    // =================== GAT (blocks 4-7, batch b) ===================
    const int b = bid - 4;
    __shared__ float adjm[NN * 129];
    __shared__ __align__(16) float gxls[NN];
    __shared__ float u[16], v[16];
    __shared__ float Wh2[NN][9];
    __shared__ float f1b[NN], f2b[NN];
    __shared__ float p[NN];

    for (int idx = tid; idx < NN * NN; idx += 768)
      adjm[(idx >> 7) * 129 + (idx & 127)] = (adj[idx] > 0) ? 1.f : 0.f;
    if (tid < NN) gxls[tid] = x[(b * SEQ + (SEQ - 1)) * NN + tid];
    if (tid < 16) {
      float uu = 0.f, vv = 0.f;
      for (int fp = 0; fp < 16; ++fp) {
        uu += emb_w[fp] * W1[fp * 16 + tid];
        vv += emb_b[fp] * W1[fp * 16 + tid];
      }
      u[tid] = uu; v[tid] = vv;
    }
    __syncthreads();
    float s1 = 0.f, t1 = 0.f, s2 = 0.f, t2 = 0.f;
    for (int f = 0; f < 16; ++f) {
      s1 += u[f] * a1[f];      t1 += v[f] * a1[f];
      s2 += u[f] * a1[16 + f]; t2 += v[f] * a1[16 + f];
    }
    if (tid < NN) {
      const int i = tid;
      const float f1i = gxls[i] * s1 + t1;
      float m = -1e30f;
      for (int j = 0; j < NN; ++j)
        if (adjm[i * 129 + j] != 0.f)
          m = fmaxf(m, lrelu(f1i + gxls[j] * s2 + t2));
      float ssum = 0.f, ps = 0.f;
      for (int j = 0; j < NN; ++j)
        if (adjm[i * 129 + j] != 0.f) {
          const float wgt = __expf(lrelu(f1i + gxls[j] * s2 + t2) - m);
          ssum += wgt; ps += wgt * gxls[j];
        }
      p[i] = ps / ssum;
    }
    __syncthreads();
    if (tid < NN) {
      const int i = tid;
      float xg1[16];
#pragma unroll
      for (int f = 0; f < 16; ++f) {
        const float ov = p[i] * u[f] + v[f];
        xg1[f] = ov > 0.f ? ov : expm1f(ov);
      }
      float wrow[8];
#pragma unroll
      for (int f2 = 0; f2 < 8; ++f2) wrow[f2] = 0.f;
#pragma unroll
      for (int f = 0; f < 16; ++f) {
        const float xv = xg1[f];
#pragma unroll
        for (int f2 = 0; f2 < 8; ++f2) wrow[f2] += xv * W2[f * 8 + f2];
      }
      float fb1 = 0.f, fb2 = 0.f;
#pragma unroll
      for (int f2 = 0; f2 < 8; ++f2) {
        Wh2[i][f2] = wrow[f2];
        fb1 += wrow[f2] * a2[f2];
        fb2 += wrow[f2] * a2[8 + f2];
      }
      f1b[i] = fb1; f2b[i] = fb2;
    }
    __syncthreads();
    if (tid < NN) {
      const int i = tid;
      const float fi = f1b[i];
      float m = -1e30f;
      for (int j = 0; j < NN; ++j)
        if (adjm[i * 129 + j] != 0.f)
          m = fmaxf(m, lrelu(fi + f2b[j]));
      float ssum = 0.f;
      float o[8];
#pragma unroll
      for (int f2 = 0; f2 < 8; ++f2) o[f2] = 0.f;
      for (int j = 0; j < NN; ++j)
        if (adjm[i * 129 + j] != 0.f) {
          const float wgt = __expf(lrelu(fi + f2b[j]) - m);
          ssum += wgt;
#pragma unroll
          for (int f2 = 0; f2 < 8; ++f2) o[f2] += wgt * Wh2[j][f2];
        }
      const float inv = 1.f / ssum;
#pragma unroll
      for (int f2 = 0; f2 < 8; ++f2)
        xg[b * (NN * 8) + i * 8 + f2] = o[f2] * inv;
    }
    __syncthreads();
    if (tid == 0)
      __hip_atomic_store(&flags[256 + b], MAGIC, __ATOMIC_RELEASE,
                         __HIP_MEMORY_SCOPE_AGENT);
    return;
  }

  // =================== CONSUMER: LSTM scan + heads (blocks 0-3) ============
  const int b   = bid;
  const int t   = tid;
  const int grp = t >> 8;            // 0,1,2 (wave-aligned)
  const int r   = t & 255;           // == uu*4 + q2
  const int uu  = r >> 2, q2 = r & 3;

  __shared__ __align__(16) float hb[2][2][HID];   // [buf][layer][unit]
  __shared__ __align__(16) float P1[2][G4];       // dbuf ih-partials
  __shared__ float cbuf[1088];
  __shared__ float hidc[96];

  const float* Wsrc = (grp == 0) ? Whh0 : (grp == 1) ? Wih1 : Whh1;
  float4 w[4][4];
#pragma unroll
  for (int j = 0; j < 4; ++j) {
    const int row = (uu + 64 * j) * HID + 16 * q2;
#pragma unroll
    for (int c = 0; c < 4; ++c)
      w[j][c] = *reinterpret_cast<const float4*>(Wsrc + row + 4 * c);
  }
  float4 b1v = make_float4(0.f, 0.f, 0.f, 0.f);
  if (grp == 2) {
    b1v.x = bih1[uu]       + bhh1[uu];
    b1v.y = bih1[uu + 64]  + bhh1[uu + 64];
    b1v.z = bih1[uu + 128] + bhh1[uu + 128];
    b1v.w = bih1[uu + 192] + bhh1[uu + 192];
  }

  if (t < 256) reinterpret_cast<float*>(hb)[t] = 0.f;   // both buffers
  float cst = 0.f;
  const float* X0b = X0T + b * G4 + uu * 4;

  // Initial frontier: flags[0..31] (32-wide parallel acquire-RMW poll).
  int c_ok;
  {
    if (t < 32) {
      while (__hip_atomic_fetch_add(&flags[t], 0, __ATOMIC_ACQUIRE,
                                    __HIP_MEMORY_SCOPE_AGENT) != MAGIC) {}
    }
    __syncthreads();   // also makes hb zeroing visible
    c_ok = 31;
  }
  float4 cur = make_float4(0.f, 0.f, 0.f, 0.f);
  if (grp == 0) cur = *reinterpret_cast<const float4*>(X0b);
  __syncthreads();

#define LSTM_STEP(TT, RB, WB)                                                  \
  do {                                                                         \
    const float4* hp = reinterpret_cast<const float4*>(                        \
        (grp == 2) ? &hb[RB][1][0] : &hb[RB][0][0]);                           \
    float4 hq[4];                                                              \
    hq[0] = hp[4 * q2 + 0]; hq[1] = hp[4 * q2 + 1];                            \
    hq[2] = hp[4 * q2 + 2]; hq[3] = hp[4 * q2 + 3];                            \
    float4 p1v = make_float4(0.f, 0.f, 0.f, 0.f);                              \
    if (grp == 2) p1v = *reinterpret_cast<const float4*>(&P1[1 - (RB)][uu * 4]); \
    float4 nxt = cur;                                                          \
    if (grp == 0 && (TT) + 1 < SEQ)                                            \
      nxt = *reinterpret_cast<const float4*>(X0b + ((TT) + 1) * (BATCH * G4)); \
    float A0 = dotacc(w[0], hq, 0.f);                                          \
    float A1 = dotacc(w[1], hq, 0.f);                                          \
    float A2 = dotacc(w[2], hq, 0.f);                                          \
    float A3 = dotacc(w[3], hq, 0.f);                                          \
    const float S0 = qsum(A0), S1 = qsum(A1), S2 = qsum(A2), S3 = qsum(A3);    \
    if (grp == 0) {                                                            \
      if ((TT) < SEQ) {                                                        \
        const float gi = fsigm(S0 + cur.x);                                    \
        const float gf = fsigm(S1 + cur.y);                                    \
        const float gg = ftanh(S2 + cur.z);                                    \
        const float go = fsigm(S3 + cur.w);                                    \
        cst = fmaf(gf, cst, gi * gg);                                          \
        if (q2 == 0) hb[WB][0][uu] = go * ftanh(cst);                          \
      }                                                                        \
    } else if (grp == 1) {                                                     \
      if ((TT) >= 1 && (TT) <= SEQ) {                                          \
        const float sel = (q2 == 0) ? S0 : (q2 == 1) ? S1 : (q2 == 2) ? S2 : S3; \
        P1[RB][r] = sel;                                                       \
      }                                                                        \
    } else {                                                                   \
      if ((TT) >= 2) {                                                         \
        const float gi = fsigm(S0 + p1v.x + b1v.x);                            \
        const float gf = fsigm(S1 + p1v.y + b1v.y);                            \
        const float gg = ftanh(S2 + p1v.z + b1v.z);                            \
        const float go = fsigm(S3 + p1v.w + b1v.w);                            \
        cst = fmaf(gf, cst, gi * gg);                                          \
        if (q2 == 0) hb[WB][1][uu] = go * ftanh(cst);                          \
      }                                                                        \
    }                                                                          \
    cur = nxt;                                                                 \
    __syncthreads();                                                           \
  } while (0)

  for (int tt = 0; tt < SEQ + 2; tt += 2) {   // TT = 0..513
    // Frontier advance: 32-wide batch every 32 steps; keeps c_ok >= tt+33.
    if (tt + 34 > c_ok && c_ok < 255) {
      const int base = c_ok + 1;
      if (t < 32 && base + t <= 255) {
        while (__hip_atomic_fetch_add(&flags[base + t], 0, __ATOMIC_ACQUIRE,
                                      __HIP_MEMORY_SCOPE_AGENT) != MAGIC) {}
      }
      __syncthreads();
      c_ok = (base + 31 < 255) ? base + 31 : 255;
    }
#pragma unroll
    for (int j = 0; j < 4; ++j) {
      pin4(w[j][0]); pin4(w[j][1]); pin4(w[j][2]); pin4(w[j][3]);
    }
    LSTM_STEP(tt, 0, 1);
    LSTM_STEP(tt + 1, 1, 0);
  }
#undef LSTM_STEP
  // grp2's last write (TT=513, WB=0): hb[0][1][*] = h1[SEQ-1] = xl_out.

  // wait for this batch's GAT result
  if (t == 0) {
    while (__hip_atomic_fetch_add(&flags[256 + b], 0, __ATOMIC_ACQUIRE,
                                  __HIP_MEMORY_SCOPE_AGENT) != MAGIC) {}
  }
  __syncthreads();

  // ---------------- fused heads: c = [h1(64) | xg_b(1024)] ----------------
  if (t < 64) cbuf[t] = hb[0][1][t];
  for (int k = t; k < 1024; k += 768) cbuf[64 + k] = xg[b * 1024 + k];
  __syncthreads();
  if (t < 96) {
    const int head = t >> 5, h = t & 31;
    const float* w1 = (head == 0) ? dw1 : (head == 1) ? rw1 : vw1;
    const float* b1 = (head == 0) ? db1 : (head == 1) ? rb1 : vb1;
    float a0 = 0.f, a1v = 0.f, a2v = 0.f, a3v = 0.f;
    for (int k = 0; k < 1088; k += 4) {
      a0  = fmaf(cbuf[k],     w1[k * 32 + h],       a0);
      a1v = fmaf(cbuf[k + 1], w1[(k + 1) * 32 + h], a1v);
      a2v = fmaf(cbuf[k + 2], w1[(k + 2) * 32 + h], a2v);
      a3v = fmaf(cbuf[k + 3], w1[(k + 3) * 32 + h], a3v);
    }
    hidc[head * 32 + h] = fmaxf(b1[h] + ((a0 + a1v) + (a2v + a3v)), 0.f);
  }
  __syncthreads();
  if (t < 4) {
    const int head2 = (t < 2) ? t : 2;
    const int o = (t < 2) ? 0 : (t - 2);
    const int odim = (t < 2) ? 1 : 2;
    const float* w2  = (head2 == 0) ? dw2 : (head2 == 1) ? rw2 : vw2;
    const float* b2p = (head2 == 0) ? db2 : (head2 == 1) ? rb2 : vb2;
    float acc = b2p[o];
    for (int hh = 0; hh < 32; ++hh)
      acc = fmaf(hidc[head2 * 32 + hh], w2[hh * odim + o], acc);
    const int off = (t == 0) ? b : (t == 1) ? (4 + b) : (8 + 2 * b + o);
    out[off] = acc;   // [dir(4) | ret(4) | vol(4x2)] flat
  }
}

// ---------------------------------------------------------------------------
extern "C" void kernel_launch(void* const* d_in, const int* in_sizes, int n_in,
                              void* d_out, int out_size, void* d_ws, size_t ws_size,
                              hipStream_t stream) {
  const float* x     = (const float*)d_in[0];
  const int*   adj   = (const int*)  d_in[1];
  const float* emb_w = (const float*)d_in[2];
  const float* emb_b = (const float*)d_in[3];
  const float* g1W   = (const float*)d_in[4];
  const float* g1a   = (const float*)d_in[5];
  const float* g2W   = (const float*)d_in[6];
  const float* g2a   = (const float*)d_in[7];
  const float* Wih0  = (const float*)d_in[8];
  const float* Whh0  = (const float*)d_in[9];
  const float* bih0  = (const float*)d_in[10];
  const float* bhh0  = (const float*)d_in[11];
  const float* Wih1  = (const float*)d_in[12];
  const float* Whh1  = (const float*)d_in[13];
  const float* bih1  = (const float*)d_in[14];
  const float* bhh1  = (const float*)d_in[15];
  const float* dw1 = (const float*)d_in[16]; const float* db1 = (const float*)d_in[17];
  const float* dw2 = (const float*)d_in[18]; const float* db2 = (const float*)d_in[19];
  const float* rw1 = (const float*)d_in[20]; const float* rb1 = (const float*)d_in[21];
  const float* rw2 = (const float*)d_in[22]; const float* rb2 = (const float*)d_in[23];
  const float* vw1 = (const float*)d_in[24]; const float* vb1 = (const float*)d_in[25];
  const float* vw2 = (const float*)d_in[26]; const float* vb2 = (const float*)d_in[27];

  float* ws = (float*)d_ws;
  float* X0 = ws;                          // SEQ*BATCH*256 floats = 2 MB (transposed)
  float* xg = ws + SEQ * BATCH * G4;       // 4096 floats
  int*  flg = (int*)(xg + BATCH * NN * 8); // 260 flag ints (0xAA-poison = not ready)
  float* out = (float*)d_out;

  hipLaunchKernelGGL(fused_all, dim3(132), dim3(768), 0, stream,
                     x, adj, emb_w, emb_b, g1W, g1a, g2W, g2a,
                     Wih0, Whh0, bih0, bhh0, Wih1, Whh1, bih1, bhh1,
                     dw1, db1, dw2, db2, rw1, rb1, rw2, rb2,
                     vw1, vb1, vw2, vb2,
                     X0, xg, flg, out);
}